// Round 6
// baseline (137.960 us; speedup 1.0000x reference)
//
#include <hip/hip_runtime.h>
#include <hip/hip_cooperative_groups.h>
#include <math.h>

namespace cg = cooperative_groups;

#define B_SZ 1024
#define C_SZ 1000
#define H_SZ 512

// ws layout (bytes):
//   [0,      4096)   int      jv[1024]       argmax index per batch row
//   [4096,   8192)   float    ymax[1024]     row max of y
//   [8192,  12288)   float    wnorm[1000]    ||w_c||^2 (fp32)
//   [16384,  81920)  float    part[16][1024] per-bx-strip row maxes
//   [524288,+1MB)    short    wbf[1000*512]  bf16 copy of w

typedef __attribute__((ext_vector_type(8))) short bf16x8;
typedef __attribute__((ext_vector_type(4))) float f32x4;

#define KC 128          // k elements per chunk
#define RS 136          // LDS row stride in shorts

// ---------------------------------------------------------------------------
// Single cooperative kernel, 256 blocks x 256 threads (1 block/CU).
// Phase 1: w->bf16 + wnorm (blocks 0..249) ; y argmax/max + y->out copy
//          (all blocks, wave-per-row, 4 rows/block).
// Phase 2: LDS-staged gathered bf16 MFMA GEMM (R5 structure, verified).
// Phase 3: reduce 16 strip partials -> last output column.
__global__ __launch_bounds__(256) void k_fused(
    const float* __restrict__ y, const float* __restrict__ w,
    const float* __restrict__ eps_p, const float* __restrict__ lip_p,
    int* __restrict__ jv, float* __restrict__ ymax,
    float* __restrict__ wnorm, short* __restrict__ wbf,
    float* __restrict__ part, float* __restrict__ out) {
    __shared__ __align__(16) short As[64 * RS];
    __shared__ __align__(16) short Bs[64 * RS];
    __shared__ int sjv[64];
    __shared__ float snj[64];
    __shared__ float sym[64];

    cg::grid_group grid = cg::this_grid();
    const int r = blockIdx.x;
    const int t = threadIdx.x;
    const int wv = t >> 6, lane = t & 63;

    // ---------------- Phase 1a: w convert + wnorm (4 rows/block) ----------
    if (r < 250) {
        const int c = r * 4 + wv;
        const float* row = w + c * H_SZ;
        float4 a = *(const float4*)(row + lane * 8);
        float4 b = *(const float4*)(row + lane * 8 + 4);
        float f[8] = {a.x, a.y, a.z, a.w, b.x, b.y, b.z, b.w};
        unsigned short u[8];
        float s = 0.f;
#pragma unroll
        for (int i = 0; i < 8; ++i) {
            s += f[i] * f[i];
            unsigned v = __float_as_uint(f[i]);
            v += 0x7fffu + ((v >> 16) & 1u);  // RNE
            u[i] = (unsigned short)(v >> 16);
        }
        uint4 pk;
        pk.x = (unsigned)u[0] | ((unsigned)u[1] << 16);
        pk.y = (unsigned)u[2] | ((unsigned)u[3] << 16);
        pk.z = (unsigned)u[4] | ((unsigned)u[5] << 16);
        pk.w = (unsigned)u[6] | ((unsigned)u[7] << 16);
        *(uint4*)(wbf + c * H_SZ + lane * 8) = pk;
#pragma unroll
        for (int off = 32; off; off >>= 1) s += __shfl_down(s, off, 64);
        if (lane == 0) wnorm[c] = s;
    }

    // ---------------- Phase 1b: y argmax/max + copy (wave-per-row) --------
    {
        const int b = r * 4 + wv;
        const float* yrow = y + b * C_SZ;
        float* orow = out + b * (C_SZ + 1);
        float best = -INFINITY;
        int bidx = 0x7fffffff;
#pragma unroll
        for (int i = 0; i < 4; ++i) {
            const int idx = i * 64 + lane;  // float4 index, 250 cover the row
            if (idx < 250) {
                float4 v = *(const float4*)(yrow + idx * 4);
                *(float4*)(orow + idx * 4) = v;
                float e[4] = {v.x, v.y, v.z, v.w};
#pragma unroll
                for (int j = 0; j < 4; ++j) {
                    if (e[j] > best) { best = e[j]; bidx = idx * 4 + j; }
                }
            }
        }
#pragma unroll
        for (int off = 32; off; off >>= 1) {
            float ov = __shfl_down(best, off, 64);
            int oi = __shfl_down(bidx, off, 64);
            if (ov > best || (ov == best && oi < bidx)) { best = ov; bidx = oi; }
        }
        if (lane == 0) {
            jv[b] = bidx;
            ymax[b] = best;
        }
    }

    grid.sync();

    // ---------------- Phase 2: GEMM + fused epilogue (R5 body) ------------
    const int by = r >> 4, bx = r & 15;
    const int b0 = by * 64, c0 = bx * 64;

    if (t < 64) {
        int j = jv[b0 + t];
        sjv[t] = j;
        snj[t] = wnorm[j];
        sym[t] = ymax[b0 + t];
    }
    __syncthreads();

    const int srow = t >> 2;  // 0..63
    const int sseg = t & 3;
    int crow = c0 + srow;
    if (crow > C_SZ - 1) crow = C_SZ - 1;
    const short* agsrc = wbf + sjv[srow] * H_SZ;
    const short* bgsrc = wbf + crow * H_SZ;

    uint4 pa[4], pb[4];
#pragma unroll
    for (int p = 0; p < 4; ++p) {
        const int off = (sseg + p * 4) * 8;
        pa[p] = *(const uint4*)(agsrc + off);
        pb[p] = *(const uint4*)(bgsrc + off);
    }

    const int col = lane & 15, quad = lane >> 4;
    const short* ard = &As[(wv * 16 + col) * RS + quad * 8];
    const short* brd = &Bs[col * RS + quad * 8];

    f32x4 acc[4] = {{0.f, 0.f, 0.f, 0.f},
                    {0.f, 0.f, 0.f, 0.f},
                    {0.f, 0.f, 0.f, 0.f},
                    {0.f, 0.f, 0.f, 0.f}};

    for (int ch = 0; ch < 4; ++ch) {
#pragma unroll
        for (int p = 0; p < 4; ++p) {
            const int off = (sseg + p * 4) * 8;
            *(uint4*)&As[srow * RS + off] = pa[p];
            *(uint4*)&Bs[srow * RS + off] = pb[p];
        }
        __syncthreads();
        if (ch < 3) {
            const int gbase = (ch + 1) * KC;
#pragma unroll
            for (int p = 0; p < 4; ++p) {
                const int off = gbase + (sseg + p * 4) * 8;
                pa[p] = *(const uint4*)(agsrc + off);
                pb[p] = *(const uint4*)(bgsrc + off);
            }
        }
#pragma unroll
        for (int ks = 0; ks < 4; ++ks) {
            bf16x8 af = *(const bf16x8*)(ard + ks * 32);
#pragma unroll
            for (int ct = 0; ct < 4; ++ct) {
                bf16x8 bf = *(const bf16x8*)(brd + ct * 16 * RS + ks * 32);
                acc[ct] = __builtin_amdgcn_mfma_f32_16x16x32_bf16(af, bf,
                                                                  acc[ct], 0, 0, 0);
            }
        }
        __syncthreads();
    }

    const float eps = *eps_p;
    const float L = *lip_p;
    const float L2 = L * L;
    float rmax[4];
#pragma unroll
    for (int i = 0; i < 4; ++i) {
        const int br = wv * 16 + quad * 4 + i;
        const int b = b0 + br;
        const float nj = snj[br];
        const float ym = sym[br];
        float m = -INFINITY;
#pragma unroll
        for (int ct = 0; ct < 4; ++ct) {
            const int cc = c0 + ct * 16 + col;
            if (cc < C_SZ) {
                const float yv = y[b * C_SZ + cc];
                const float nc = wnorm[cc];
                const float sq = L2 * (nj + nc - 2.0f * acc[ct][i]);
                const float K = sq > 0.f ? sqrtf(sq) : 0.f;
                const float cand = (yv == ym) ? -INFINITY : yv + eps * K;
                m = fmaxf(m, cand);
            }
        }
        rmax[i] = m;
    }
#pragma unroll
    for (int off = 8; off; off >>= 1)
#pragma unroll
        for (int i = 0; i < 4; ++i)
            rmax[i] = fmaxf(rmax[i], __shfl_xor(rmax[i], off, 64));
    if (col == 0) {
        float* slice = part + bx * B_SZ;
#pragma unroll
        for (int i = 0; i < 4; ++i)
            slice[b0 + wv * 16 + quad * 4 + i] = rmax[i];
    }

    grid.sync();

    // ---------------- Phase 3: final reduce (wave-per-row, 4 rows/block) --
    {
        const int rr = r * 4 + wv;
        float m = -INFINITY;
        if (lane < 16) m = part[lane * B_SZ + rr];
#pragma unroll
        for (int off = 8; off; off >>= 1)
            m = fmaxf(m, __shfl_xor(m, off, 64));
        if (lane == 0) out[rr * (C_SZ + 1) + C_SZ] = m;
    }
}

// ---------------------------------------------------------------------------
extern "C" void kernel_launch(void* const* d_in, const int* in_sizes, int n_in,
                              void* d_out, int out_size, void* d_ws,
                              size_t ws_size, hipStream_t stream) {
    const float* y = (const float*)d_in[0];
    const float* w = (const float*)d_in[1];
    const float* eps = (const float*)d_in[2];
    const float* lip = (const float*)d_in[3];
    float* out = (float*)d_out;

    char* ws = (char*)d_ws;
    int* jv = (int*)ws;
    float* ymax = (float*)(ws + 4096);
    float* wnorm = (float*)(ws + 8192);
    float* part = (float*)(ws + 16384);
    short* wbf = (short*)(ws + 524288);

    void* args[] = {(void*)&y,    (void*)&w,    (void*)&eps,  (void*)&lip,
                    (void*)&jv,   (void*)&ymax, (void*)&wnorm, (void*)&wbf,
                    (void*)&part, (void*)&out};
    hipLaunchCooperativeKernel((void*)k_fused, dim3(256), dim3(256), args, 0,
                               stream);
}

// Round 7
// 86.277 us; speedup vs baseline: 1.5990x; 1.5990x over previous
//
#include <hip/hip_runtime.h>
#include <math.h>

#define B_SZ 1024
#define C_SZ 1000
#define H_SZ 512

// ws layout (bytes):
//   [0,      4096)   int      jv[1024]       argmax index per batch row
//   [4096,   8192)   float    ymax[1024]     row max of y
//   [8192,  12288)   float    wnorm[1000]    ||w_c||^2 (fp32)
//   [16384,  81920)  float    part[16][1024] per-bx-strip row maxes
//   [524288,+1MB)    short    wbf[1000*512]  bf16 copy of w

typedef __attribute__((ext_vector_type(8))) short bf16x8;
typedef __attribute__((ext_vector_type(4))) float f32x4;

#define KC 128          // k elements per chunk
#define RS 136          // LDS row stride in shorts (+8 pad)

// ---------------------------------------------------------------------------
// K1 prep (identical to R5), role by blockIdx.x:
//   [0,250):    wnorm + f32->bf16 convert, 4 w-rows per block (1 wave/row)
//   [250,1274): argmax/max of one y row + coalesced y->out copy
__global__ __launch_bounds__(256) void k_prep(
    const float* __restrict__ y, const float* __restrict__ w,
    int* __restrict__ jv, float* __restrict__ ymax,
    float* __restrict__ wnorm, short* __restrict__ wbf,
    float* __restrict__ out) {
    const int r = blockIdx.x;
    const int tid = threadIdx.x;
    if (r < 250) {
        const int wave = tid >> 6, lane = tid & 63;
        const int c = r * 4 + wave;
        const float* row = w + c * H_SZ;
        float4 a = *(const float4*)(row + lane * 8);
        float4 b = *(const float4*)(row + lane * 8 + 4);
        float f[8] = {a.x, a.y, a.z, a.w, b.x, b.y, b.z, b.w};
        unsigned short u[8];
        float s = 0.f;
#pragma unroll
        for (int i = 0; i < 8; ++i) {
            s += f[i] * f[i];
            unsigned v = __float_as_uint(f[i]);
            v += 0x7fffu + ((v >> 16) & 1u);  // RNE
            u[i] = (unsigned short)(v >> 16);
        }
        uint4 pk;
        pk.x = (unsigned)u[0] | ((unsigned)u[1] << 16);
        pk.y = (unsigned)u[2] | ((unsigned)u[3] << 16);
        pk.z = (unsigned)u[4] | ((unsigned)u[5] << 16);
        pk.w = (unsigned)u[6] | ((unsigned)u[7] << 16);
        *(uint4*)(wbf + c * H_SZ + lane * 8) = pk;
#pragma unroll
        for (int off = 32; off; off >>= 1) s += __shfl_down(s, off, 64);
        if (lane == 0) wnorm[c] = s;
    } else {
        const int b = r - 250;
        const float* yrow = y + b * C_SZ;
        float* orow = out + b * (C_SZ + 1);
        float best = -INFINITY;
        int bidx = 0x7fffffff;
        if (tid < 250) {
            float4 v = *(const float4*)(yrow + tid * 4);
            float e[4] = {v.x, v.y, v.z, v.w};
#pragma unroll
            for (int i = 0; i < 4; ++i) {
                orow[tid * 4 + i] = e[i];
                if (e[i] > best) { best = e[i]; bidx = tid * 4 + i; }
            }
        }
        const int lane = tid & 63;
#pragma unroll
        for (int off = 32; off; off >>= 1) {
            float ov = __shfl_down(best, off, 64);
            int oi = __shfl_down(bidx, off, 64);
            if (ov > best || (ov == best && oi < bidx)) { best = ov; bidx = oi; }
        }
        __shared__ float sv[4];
        __shared__ int si[4];
        if (lane == 0) { sv[tid >> 6] = best; si[tid >> 6] = bidx; }
        __syncthreads();
        if (tid == 0) {
            float bv = sv[0]; int bi = si[0];
#pragma unroll
            for (int k = 1; k < 4; ++k) {
                if (sv[k] > bv || (sv[k] == bv && si[k] < bi)) { bv = sv[k]; bi = si[k]; }
            }
            jv[b] = bi;
            ymax[b] = bv;
        }
    }
}

// ---------------------------------------------------------------------------
// K2: LDS-staged gathered bf16 MFMA GEMM + fused epilogue.
// NEW decomposition: block tile 16(b) x 64(c), grid (16,64) = 1024 blocks =
// 4 blocks/CU = 16 waves/CU (was 1 block/CU -> zero latency hiding).
// K staged in 4 chunks of 128, register-prefetched one chunk ahead.
// Wave wv computes c-subtile wv (16 cols) with mfma_f32_16x16x32_bf16
// (operand/epilogue layouts carried unchanged from the verified R5 kernel).
__global__ __launch_bounds__(256) void k_main(
    const float* __restrict__ y, const short* __restrict__ wbf,
    const float* __restrict__ eps_p, const float* __restrict__ lip_p,
    const int* __restrict__ jv, const float* __restrict__ ymax,
    const float* __restrict__ wnorm, float* __restrict__ part) {
    __shared__ __align__(16) short As[16 * RS];
    __shared__ __align__(16) short Bs[64 * RS];
    __shared__ int sjv[16];
    __shared__ float snj[16];
    __shared__ float sym[16];
    __shared__ float wred[4][16];

    const int t = threadIdx.x;
    const int wv = t >> 6, lane = t & 63;
    const int col = lane & 15, quad = lane >> 4;
    const int bx = blockIdx.x, by = blockIdx.y;
    const int b0 = by * 16, c0 = bx * 64;

    if (t < 16) {
        int j = jv[b0 + t];
        sjv[t] = j;
        snj[t] = wnorm[j];
        sym[t] = ymax[b0 + t];
    }
    __syncthreads();

    // Staging assignment.
    // A: 16 rows x 16 segs of 8 shorts = 256 -> one 16B load per thread.
    const int arow = t >> 4;   // 0..15
    const int aseg = t & 15;   // 0..15
    const short* ag = wbf + sjv[arow] * H_SZ + aseg * 8;
    // B: 64 rows x 16 segs = 1024 -> four 16B loads per thread.
    int browv[4], bsegv[4];
    const short* bg[4];
#pragma unroll
    for (int p = 0; p < 4; ++p) {
        const int idx = p * 256 + t;
        browv[p] = idx >> 4;   // 0..63
        bsegv[p] = idx & 15;
        int cr = c0 + browv[p];
        if (cr > C_SZ - 1) cr = C_SZ - 1;
        bg[p] = wbf + cr * H_SZ + bsegv[p] * 8;
    }

    uint4 pa = *(const uint4*)ag;
    uint4 pb[4];
#pragma unroll
    for (int p = 0; p < 4; ++p) pb[p] = *(const uint4*)bg[p];

    const short* ard = &As[col * RS + quad * 8];
    const short* brd = &Bs[(wv * 16 + col) * RS + quad * 8];

    f32x4 acc = {0.f, 0.f, 0.f, 0.f};

    for (int ch = 0; ch < 4; ++ch) {
        *(uint4*)&As[arow * RS + aseg * 8] = pa;
#pragma unroll
        for (int p = 0; p < 4; ++p)
            *(uint4*)&Bs[browv[p] * RS + bsegv[p] * 8] = pb[p];
        __syncthreads();
        if (ch < 3) {
            const int go = (ch + 1) * KC;
            pa = *(const uint4*)(ag + go);
#pragma unroll
            for (int p = 0; p < 4; ++p) pb[p] = *(const uint4*)(bg[p] + go);
        }
#pragma unroll
        for (int ks = 0; ks < 4; ++ks) {
            bf16x8 af = *(const bf16x8*)(ard + ks * 32);
            bf16x8 bf = *(const bf16x8*)(brd + ks * 32);
            acc = __builtin_amdgcn_mfma_f32_16x16x32_bf16(af, bf, acc, 0, 0, 0);
        }
        __syncthreads();
    }

    // Epilogue. C/D layout: col=lane&15 (class), row=quad*4+reg (batch).
    const float eps = *eps_p;
    const float L = *lip_p;
    const float L2 = L * L;
    const int cc = c0 + wv * 16 + col;
    const float nc = wnorm[cc < C_SZ ? cc : C_SZ - 1];
    float rmax[4];
#pragma unroll
    for (int i = 0; i < 4; ++i) {
        const int br = quad * 4 + i;
        const int b = b0 + br;
        float cand = -INFINITY;
        if (cc < C_SZ) {
            const float yv = y[b * C_SZ + cc];
            const float sq = L2 * (snj[br] + nc - 2.0f * acc[i]);
            const float K = sq > 0.f ? sqrtf(sq) : 0.f;
            cand = (yv == sym[br]) ? -INFINITY : yv + eps * K;
        }
        rmax[i] = cand;
    }
#pragma unroll
    for (int off = 8; off; off >>= 1)
#pragma unroll
        for (int i = 0; i < 4; ++i)
            rmax[i] = fmaxf(rmax[i], __shfl_xor(rmax[i], off, 64));
    if (col == 0) {
#pragma unroll
        for (int i = 0; i < 4; ++i) wred[wv][quad * 4 + i] = rmax[i];
    }
    __syncthreads();
    if (t < 16) {
        float m = fmaxf(fmaxf(wred[0][t], wred[1][t]),
                        fmaxf(wred[2][t], wred[3][t]));
        part[bx * B_SZ + b0 + t] = m;
    }
}

// ---------------------------------------------------------------------------
// K3: reduce the 16 per-strip partial maxes into the last output column.
__global__ void k_final(const float* __restrict__ part,
                        float* __restrict__ out) {
    int b = blockIdx.x * 256 + threadIdx.x;
    if (b >= B_SZ) return;
    float m = -INFINITY;
#pragma unroll
    for (int s = 0; s < 16; ++s) m = fmaxf(m, part[s * B_SZ + b]);
    out[b * (C_SZ + 1) + C_SZ] = m;
}

// ---------------------------------------------------------------------------
extern "C" void kernel_launch(void* const* d_in, const int* in_sizes, int n_in,
                              void* d_out, int out_size, void* d_ws,
                              size_t ws_size, hipStream_t stream) {
    const float* y = (const float*)d_in[0];
    const float* w = (const float*)d_in[1];
    const float* eps = (const float*)d_in[2];
    const float* lip = (const float*)d_in[3];
    float* out = (float*)d_out;

    char* ws = (char*)d_ws;
    int* jv = (int*)ws;
    float* ymax = (float*)(ws + 4096);
    float* wnorm = (float*)(ws + 8192);
    float* part = (float*)(ws + 16384);
    short* wbf = (short*)(ws + 524288);

    k_prep<<<250 + B_SZ, 256, 0, stream>>>(y, w, jv, ymax, wnorm, wbf, out);
    k_main<<<dim3(16, 64), 256, 0, stream>>>(y, wbf, eps, lip, jv, ymax, wnorm,
                                             part);
    k_final<<<(B_SZ + 255) / 256, 256, 0, stream>>>(part, out);
}

// Round 9
// 82.798 us; speedup vs baseline: 1.6662x; 1.0420x over previous
//
#include <hip/hip_runtime.h>
#include <math.h>

#define B_SZ 1024
#define C_SZ 1000
#define H_SZ 512

// ws layout (bytes):
//   [0, 65536)  float part[16][1024]  per-bx-strip row maxes (agent-scope atomics)

typedef __attribute__((ext_vector_type(8))) short bf16x8;
typedef __attribute__((ext_vector_type(4))) float f32x4;

#define KC 128          // k elements per chunk
#define RS 136          // LDS row stride in shorts (+8 pad)

// fp32x8 -> bf16x8 (RNE)
__device__ __forceinline__ uint4 pack8(float4 a, float4 b) {
    unsigned e[8] = {__float_as_uint(a.x), __float_as_uint(a.y),
                     __float_as_uint(a.z), __float_as_uint(a.w),
                     __float_as_uint(b.x), __float_as_uint(b.y),
                     __float_as_uint(b.z), __float_as_uint(b.w)};
    unsigned short h[8];
#pragma unroll
    for (int i = 0; i < 8; ++i) {
        unsigned v = e[i];
        v += 0x7fffu + ((v >> 16) & 1u);
        h[i] = (unsigned short)(v >> 16);
    }
    uint4 p;
    p.x = (unsigned)h[0] | ((unsigned)h[1] << 16);
    p.y = (unsigned)h[2] | ((unsigned)h[3] << 16);
    p.z = (unsigned)h[4] | ((unsigned)h[5] << 16);
    p.w = (unsigned)h[6] | ((unsigned)h[7] << 16);
    return p;
}

__device__ __forceinline__ float sumsq8(float4 a, float4 b) {
    return a.x * a.x + a.y * a.y + a.z * a.z + a.w * a.w +
           b.x * b.x + b.y * b.y + b.z * b.z + b.w * b.w;
}

// ---------------------------------------------------------------------------
// K1: fully self-contained gathered bf16 MFMA GEMM + fused epilogue.
// NO cross-kernel ws reads: per-block in-block argmax of its 16 y-rows,
// row norms accumulated in fp32 during staging. Block tile 16(b) x 64(c),
// grid (16,64) = 1024 blocks = 4 blocks/CU. K in 4 chunks of 128, fp32
// register-prefetched one chunk ahead. MFMA core/epilogue = verified R8.
// part written with agent-scope atomic stores (cross-XCD-safe payload).
__global__ __launch_bounds__(256) void k_main(
    const float* __restrict__ y, const float* __restrict__ w,
    const float* __restrict__ eps_p, const float* __restrict__ lip_p,
    float* __restrict__ part) {
    __shared__ __align__(16) short As[16 * RS];
    __shared__ __align__(16) short Bs[64 * RS];
    __shared__ int sjv[16];
    __shared__ float sym[16];
    __shared__ float snj[16];
    __shared__ float snc[64];
    __shared__ float wred[4][16];

    const int t = threadIdx.x;
    const int wv = t >> 6, lane = t & 63;
    const int col = lane & 15, quad = lane >> 4;
    const int bx = blockIdx.x, by = blockIdx.y;
    const int b0 = by * 16, c0 = bx * 64;

    // ---- Phase A: in-block argmax/max of the 16 y-rows (16 thr/row) ------
    {
        const int lr = t >> 4, seg = t & 15;
        const float* yrow = y + (b0 + lr) * C_SZ;
        float best = -INFINITY;
        int bidx = 0x7fffffff;
#pragma unroll
        for (int i = 0; i < 16; ++i) {
            const int idx = seg + i * 16;  // float4 index; 250 cover the row
            if (idx < 250) {
                float4 v = *(const float4*)(yrow + idx * 4);
                float e[4] = {v.x, v.y, v.z, v.w};
#pragma unroll
                for (int j = 0; j < 4; ++j) {
                    if (e[j] > best) { best = e[j]; bidx = idx * 4 + j; }
                }
            }
        }
        // reduce across the 16 lanes of this row group (first index on ties)
#pragma unroll
        for (int off = 8; off; off >>= 1) {
            float ov = __shfl_xor(best, off, 64);
            int oi = __shfl_xor(bidx, off, 64);
            if (ov > best || (ov == best && oi < bidx)) { best = ov; bidx = oi; }
        }
        if (seg == 0) { sjv[lr] = bidx; sym[lr] = best; }
    }
    __syncthreads();

    // ---- Staging pointers (fp32 source, convert on LDS write) ------------
    const int arow = t >> 4;   // 0..15
    const int aseg = t & 15;   // 0..15
    const float* ag = w + sjv[arow] * H_SZ + aseg * 8;
    int brow_[4];
    const float* bg[4];
#pragma unroll
    for (int p = 0; p < 4; ++p) {
        const int idx = p * 256 + t;
        brow_[p] = idx >> 4;   // 0..63 (aseg is the seg for all p)
        int cr = c0 + brow_[p];
        if (cr > C_SZ - 1) cr = C_SZ - 1;
        bg[p] = w + cr * H_SZ + aseg * 8;
    }

    float4 pa0 = *(const float4*)ag;
    float4 pa1 = *(const float4*)(ag + 4);
    float4 pb0[4], pb1[4];
#pragma unroll
    for (int p = 0; p < 4; ++p) {
        pb0[p] = *(const float4*)bg[p];
        pb1[p] = *(const float4*)(bg[p] + 4);
    }

    const short* ard = &As[col * RS + quad * 8];
    const short* brd = &Bs[(wv * 16 + col) * RS + quad * 8];

    f32x4 acc = {0.f, 0.f, 0.f, 0.f};
    float na = 0.f;
    float nb[4] = {0.f, 0.f, 0.f, 0.f};

    for (int ch = 0; ch < 4; ++ch) {
        na += sumsq8(pa0, pa1);
        *(uint4*)&As[arow * RS + aseg * 8] = pack8(pa0, pa1);
#pragma unroll
        for (int p = 0; p < 4; ++p) {
            nb[p] += sumsq8(pb0[p], pb1[p]);
            *(uint4*)&Bs[brow_[p] * RS + aseg * 8] = pack8(pb0[p], pb1[p]);
        }
        __syncthreads();
        if (ch < 3) {
            const int go = (ch + 1) * KC;
            pa0 = *(const float4*)(ag + go);
            pa1 = *(const float4*)(ag + go + 4);
#pragma unroll
            for (int p = 0; p < 4; ++p) {
                pb0[p] = *(const float4*)(bg[p] + go);
                pb1[p] = *(const float4*)(bg[p] + go + 4);
            }
        }
#pragma unroll
        for (int ks = 0; ks < 4; ++ks) {
            bf16x8 af = *(const bf16x8*)(ard + ks * 32);
            bf16x8 bf = *(const bf16x8*)(brd + ks * 32);
            acc = __builtin_amdgcn_mfma_f32_16x16x32_bf16(af, bf, acc, 0, 0, 0);
        }
        __syncthreads();
    }

    // ---- Norm reductions (16-lane xor groups, all in-wave) ---------------
#pragma unroll
    for (int off = 1; off < 16; off <<= 1) na += __shfl_xor(na, off, 64);
#pragma unroll
    for (int p = 0; p < 4; ++p)
#pragma unroll
        for (int off = 1; off < 16; off <<= 1)
            nb[p] += __shfl_xor(nb[p], off, 64);
    if (aseg == 0) {
        snj[arow] = na;
#pragma unroll
        for (int p = 0; p < 4; ++p) snc[brow_[p]] = nb[p];
    }
    __syncthreads();

    // ---- Epilogue (verified). C/D: col=lane&15 (class), row=quad*4+reg ---
    const float eps = *eps_p;
    const float L = *lip_p;
    const float L2 = L * L;
    const int cc = c0 + wv * 16 + col;
    const float nc = snc[wv * 16 + col];
    float rmax[4];
#pragma unroll
    for (int i = 0; i < 4; ++i) {
        const int br = quad * 4 + i;
        const int b = b0 + br;
        float cand = -INFINITY;
        if (cc < C_SZ) {
            const float yv = y[b * C_SZ + cc];
            const float sq = L2 * (snj[br] + nc - 2.0f * acc[i]);
            const float K = sq > 0.f ? sqrtf(sq) : 0.f;
            cand = (yv == sym[br]) ? -INFINITY : yv + eps * K;
        }
        rmax[i] = cand;
    }
#pragma unroll
    for (int off = 8; off; off >>= 1)
#pragma unroll
        for (int i = 0; i < 4; ++i)
            rmax[i] = fmaxf(rmax[i], __shfl_xor(rmax[i], off, 64));
    if (col == 0) {
#pragma unroll
        for (int i = 0; i < 4; ++i) wred[wv][quad * 4 + i] = rmax[i];
    }
    __syncthreads();
    if (t < 16) {
        float m = fmaxf(fmaxf(wred[0][t], wred[1][t]),
                        fmaxf(wred[2][t], wred[3][t]));
        __hip_atomic_store(&part[bx * B_SZ + b0 + t], m, __ATOMIC_RELAXED,
                           __HIP_MEMORY_SCOPE_AGENT);
    }
}

// ---------------------------------------------------------------------------
// K2: y->out copy (pure input) + reduce the 16 strip maxes (agent-scope
// atomic loads) into the last output column. Wave per row, 4 rows/block.
__global__ __launch_bounds__(256) void k_final(const float* __restrict__ y,
                                               float* __restrict__ part,
                                               float* __restrict__ out) {
    const int t = threadIdx.x;
    const int wv = t >> 6, lane = t & 63;
    const int b = blockIdx.x * 4 + wv;
    const float* yrow = y + b * C_SZ;
    float* orow = out + b * (C_SZ + 1);
#pragma unroll
    for (int i = 0; i < 4; ++i) {
        const int idx = i * 64 + lane;  // float4 index; 250 cover the row
        if (idx < 250)
            *(float4*)(orow + idx * 4) = *(const float4*)(yrow + idx * 4);
    }
    float m = -INFINITY;
    if (lane < 16)
        m = __hip_atomic_load(&part[lane * B_SZ + b], __ATOMIC_RELAXED,
                              __HIP_MEMORY_SCOPE_AGENT);
#pragma unroll
    for (int off = 8; off; off >>= 1) m = fmaxf(m, __shfl_xor(m, off, 64));
    if (lane == 0) orow[C_SZ] = m;
}

// ---------------------------------------------------------------------------
extern "C" void kernel_launch(void* const* d_in, const int* in_sizes, int n_in,
                              void* d_out, int out_size, void* d_ws,
                              size_t ws_size, hipStream_t stream) {
    const float* y = (const float*)d_in[0];
    const float* w = (const float*)d_in[1];
    const float* eps = (const float*)d_in[2];
    const float* lip = (const float*)d_in[3];
    float* out = (float*)d_out;
    float* part = (float*)d_ws;

    k_main<<<dim3(16, 64), 256, 0, stream>>>(y, w, eps, lip, part);
    k_final<<<B_SZ / 4, 256, 0, stream>>>(y, part, out);
}